// Round 8
// baseline (81.648 us; speedup 1.0000x reference)
//
#include <hip/hip_runtime.h>

// Reference is ifft2(fft2(x)) with cancelling transposes == identity on the
// input (FFT roundoff ~1.6e-2 << threshold 1.08e-1). Pure fp32 copy of
// 32*512*512*8 floats = 256 MiB each way.
//
// R1: float4 grid-stride, 2048 blocks        -> 111.5 us (4.8 TB/s)
// R3: +unroll +NT loads AND stores           -> 120.9 us (NT loads hurt)
// R4: hipMemcpyAsync d2d blit                -> 104.7 us (5.13 TB/s)
// R5: 4x float4/thread, no NT                ->  98.8 us (5.43 TB/s)
// R6: 8x float4/thread                       ->  99.7 us (MLP saturated @HBM)
// R7: NT stores only (input stays L3-hot)    ->  81.5 us (6.59 TB/s eff.)
// R8: R7 + 8-deep load batch. Read regime changed (L3 hits, ~200cy), so
//     re-test MLP depth. Floor model: 268 MB writes @7 TB/s = 38 us.

typedef float f32x4 __attribute__((ext_vector_type(4)));

__global__ __launch_bounds__(256) void copy_f4x8_nts_kernel(
        const f32x4* __restrict__ in,
        f32x4* __restrict__ out,
        int n4) {
    int base = blockIdx.x * (blockDim.x * 8) + threadIdx.x;
    int b7 = base + 7 * 256;
    if (b7 < n4) {
        f32x4 a0 = in[base + 0 * 256];   // cacheable: keep input in L3
        f32x4 a1 = in[base + 1 * 256];
        f32x4 a2 = in[base + 2 * 256];
        f32x4 a3 = in[base + 3 * 256];
        f32x4 a4 = in[base + 4 * 256];
        f32x4 a5 = in[base + 5 * 256];
        f32x4 a6 = in[base + 6 * 256];
        f32x4 a7 = in[base + 7 * 256];
        __builtin_nontemporal_store(a0, &out[base + 0 * 256]);
        __builtin_nontemporal_store(a1, &out[base + 1 * 256]);
        __builtin_nontemporal_store(a2, &out[base + 2 * 256]);
        __builtin_nontemporal_store(a3, &out[base + 3 * 256]);
        __builtin_nontemporal_store(a4, &out[base + 4 * 256]);
        __builtin_nontemporal_store(a5, &out[base + 5 * 256]);
        __builtin_nontemporal_store(a6, &out[base + 6 * 256]);
        __builtin_nontemporal_store(a7, &out[base + 7 * 256]);
    } else {
        #pragma unroll
        for (int j = 0; j < 8; ++j) {
            int b = base + j * 256;
            if (b < n4) __builtin_nontemporal_store(in[b], &out[b]);
        }
    }
}

extern "C" void kernel_launch(void* const* d_in, const int* in_sizes, int n_in,
                              void* d_out, int out_size, void* d_ws, size_t ws_size,
                              hipStream_t stream) {
    const f32x4* in = (const f32x4*)d_in[0];
    f32x4* out = (f32x4*)d_out;
    int n = in_sizes[0];          // 67,108,864 floats
    int n4 = n >> 2;              // 16,777,216 float4s

    const int block = 256;
    int grid = (n4 + block * 8 - 1) / (block * 8);   // 8192 blocks

    copy_f4x8_nts_kernel<<<grid, block, 0, stream>>>(in, out, n4);
}